// Round 10
// baseline (467.524 us; speedup 1.0000x reference)
//
#include <hip/hip_runtime.h>
#include <math.h>

// ---------------------------------------------------------------------------
// Swin block, bf16-MFMA, MI355X. B=32 H=W=56 C=192 NH=6 hd=32 WS=7 SS=3.
// T=100352. GEMMs: 16x16x32 bf16 MFMA, fp32 accum. LN/softmax/GELU/residual
// in fp32. Weights repacked per-launch into MFMA B-fragment order (bf16).
// Round 16: round-15 regressed because __syncthreads() is a FULL vmcnt(0)
// drain -- the per-phase prefetch was drained at the very next barrier
// (48 drains/block). T4 fix: counted vmcnt + raw s_barrier. 3-buffer ring
// SB[3][6144]: each phase stages chunk p+1, waits vmcnt(3) (chunk p done,
// chunk p+1 STAYS IN FLIGHT), one raw barrier, computes chunk p. Stage at
// phase p overwrites the buffer last read at p-2; barrier p-1 makes that
// race-free with a single barrier per phase. LDS 40KB -> 4 blocks/CU.
// ---------------------------------------------------------------------------

constexpr long T = 100352;

typedef __attribute__((ext_vector_type(8))) short short8;   // 8 bf16
typedef __attribute__((ext_vector_type(4))) float f32x4;    // MFMA acc

__device__ __forceinline__ short bf16(float f) {
    union { float f; unsigned u; } v; v.f = f;
    return (short)((v.u + 0x7fff + ((v.u >> 16) & 1)) >> 16);
}

__device__ __forceinline__ void gll16(const void* g, void* l) {
    __builtin_amdgcn_global_load_lds(
        (const __attribute__((address_space(1))) void*)g,
        (__attribute__((address_space(3))) void*)l, 16, 0, 0);
}

// ---------------- merged prep: packs + bias table + LN1 stats --------------
// bid <  432 : qkv pack (K=192,N=576)
// bid <  576 : proj pack (K=192,N=192, [ks][nt])
// bid < 1152 : fc1 pack (K=192,N=768)
// bid < 1728 : fc2 pack (K=768,N=192, [t][ks][nt] -- ks-halves contiguous)
// bid < 1954 : rel-pos-bias + shift-mask table
// else       : LN1 per-token stats (4 tokens/block)
__global__ __launch_bounds__(256)
void prep_k(const float* __restrict__ qkv_w, const float* __restrict__ proj_w,
            const float* __restrict__ fc1_w, const float* __restrict__ fc2_w,
            const float* __restrict__ relb, const float* __restrict__ x,
            short* __restrict__ qkvP, short* __restrict__ projP,
            short* __restrict__ fc1P, short* __restrict__ fc2P,
            float* __restrict__ bm, float* __restrict__ mean,
            float* __restrict__ rstd)
{
    const int bid = blockIdx.x;
    const int tid = threadIdx.x;
    if (bid < 432) {                    // qkv
        const int idx = bid * 256 + tid;
        const int k = idx / 576, n = idx - k * 576;
        const int flat = (((n >> 4) * 6 + (k >> 5)) * 64 +
                          (((k >> 3) & 3) << 4) + (n & 15)) * 8 + (k & 7);
        qkvP[flat] = bf16(qkv_w[idx]);
    } else if (bid < 576) {             // proj
        const int idx = (bid - 432) * 256 + tid;
        const int k = idx / 192, n = idx - k * 192;
        const int flat = ((((k >> 5) * 12 + (n >> 4)) * 64) +
                          (((k >> 3) & 3) << 4) + (n & 15)) * 8 + (k & 7);
        projP[flat] = bf16(proj_w[idx]);
    } else if (bid < 1152) {            // fc1
        const int idx = (bid - 576) * 256 + tid;
        const int k = idx / 768, n = idx - k * 768;
        const int flat = (((n >> 4) * 6 + (k >> 5)) * 64 +
                          (((k >> 3) & 3) << 4) + (n & 15)) * 8 + (k & 7);
        fc1P[flat] = bf16(fc1_w[idx]);
    } else if (bid < 1728) {            // fc2 [t][ks][nt]
        const int idx = (bid - 1152) * 256 + tid;
        const int k = idx / 192, n = idx - k * 192;
        const int t = k >> 6, ks = (k >> 5) & 1, nt = n >> 4;
        const int flat = (((t * 2 + ks) * 12 + nt) * 64 +
                          (((k >> 3) & 3) << 4) + (n & 15)) * 8 + (k & 7);
        fc2P[flat] = bf16(fc2_w[idx]);
    } else if (bid < 1954) {            // bias+mask table
        const int idx = (bid - 1728) * 256 + tid;
        if (idx >= 6 * 4 * 2401) return;
        const int e = idx % 2401, rest = idx / 2401;
        const int tw = rest & 1, th = (rest >> 1) & 1, head = rest >> 2;
        const int i = e / 49, j = e - i * 49;
        const int yi = i / 7, xi = i - yi * 7, yj = j / 7, xj = j - yj * 7;
        const float v = relb[((yi - yj + 6) * 13 + (xi - xj + 6)) * 6 + head];
        const int hi = th ? 49 + yi : yi, hj = th ? 49 + yj : yj;
        const int wa = tw ? 49 + xi : xi, wb = tw ? 49 + xj : xj;
        const int Li = (hi < 49 ? 0 : (hi < 53 ? 1 : 2)) * 3 + (wa < 49 ? 0 : (wa < 53 ? 1 : 2));
        const int Lj = (hj < 49 ? 0 : (hj < 53 ? 1 : 2)) * 3 + (wb < 49 ? 0 : (wb < 53 ? 1 : 2));
        bm[idx] = (Li != Lj) ? v - 100.0f : v;
    } else {                            // LN1 stats
        const int wave = tid >> 6;
        const int lane = tid & 63;
        const long tok = (long)(bid - 1954) * 4 + wave;
        const float* p = x + tok * 192;
        const float a = p[lane], b = p[lane + 64], c = p[lane + 128];
        float s = a + b + c;
        float q = a * a + b * b + c * c;
        #pragma unroll
        for (int off = 32; off > 0; off >>= 1) {
            s += __shfl_xor(s, off);
            q += __shfl_xor(q, off);
        }
        if (lane == 0) {
            const float m = s * (1.0f / 192.0f);
            const float v = q * (1.0f / 192.0f) - m * m;
            mean[tok] = m;
            rstd[tok] = 1.0f / sqrtf(v + 1e-5f);
        }
    }
}

// ---------------- fused LN1+shift+window+QKV+MFMA attention ----------------
// (round 14: head loop fully unrolled so oa[]/qfrag[] are statically indexed;
// per-head double-buffered K/V, LDS 24KB, single 768B row write at end)
__global__ __launch_bounds__(256, 3)
void winattn_k(const float* __restrict__ x, const float* __restrict__ n1g,
               const float* __restrict__ n1b, const short* __restrict__ qkvP,
               const float* __restrict__ qkv_b, const float* __restrict__ bm,
               const float* __restrict__ mean, const float* __restrict__ rstd,
               float* __restrict__ outp)
{
    __shared__ __align__(16) short Kb[2][2048];
    __shared__ __align__(16) short Vb[2][2048];
    __shared__ __align__(16) short Pf[4][1024];
    const int bw  = blockIdx.x;
    const int tid = threadIdx.x;
    const int b = bw >> 6, wi = bw & 63, wh = wi >> 3, ww = wi & 7;
    const int wave = tid >> 6, lane = tid & 63;
    const int col = lane & 15, rbase = (lane >> 4) << 2;
    const float scale = 0.17677669529663687f;

    const int am = lane & 15;
    const int arow = (wave << 4) + am;
    const int kof = (lane >> 4) << 3;
    short8 afr[6];
    long tokA = 0; float mA = 0.f, rsA = 1.f;
    const bool avalid = arow < 49;
    if (avalid) {
        const int yi = arow / 7, xi = arow - yi * 7;
        int h = wh * 7 + yi + 3; if (h >= 56) h -= 56;
        int w = ww * 7 + xi + 3; if (w >= 56) w -= 56;
        tokA = (long)b * 3136 + h * 56 + w;
        mA = mean[tokA]; rsA = rstd[tokA];
    }
    #pragma unroll
    for (int ks = 0; ks < 6; ++ks) {
        short8 a = {};
        if (avalid) {
            const int k0 = (ks << 5) + kof;
            const float4 v0 = *(const float4*)(x + tokA * 192 + k0);
            const float4 v1 = *(const float4*)(x + tokA * 192 + k0 + 4);
            const float4 g0 = *(const float4*)(n1g + k0);
            const float4 g1 = *(const float4*)(n1g + k0 + 4);
            const float4 e0 = *(const float4*)(n1b + k0);
            const float4 e1 = *(const float4*)(n1b + k0 + 4);
            a[0] = bf16((v0.x - mA) * rsA * g0.x + e0.x);
            a[1] = bf16((v0.y - mA) * rsA * g0.y + e0.y);
            a[2] = bf16((v0.z - mA) * rsA * g0.z + e0.z);
            a[3] = bf16((v0.w - mA) * rsA * g0.w + e0.w);
            a[4] = bf16((v1.x - mA) * rsA * g1.x + e1.x);
            a[5] = bf16((v1.y - mA) * rsA * g1.y + e1.y);
            a[6] = bf16((v1.z - mA) * rsA * g1.z + e1.z);
            a[7] = bf16((v1.w - mA) * rsA * g1.w + e1.w);
        }
        afr[ks] = a;
    }

    // ---- Q for all heads (wave-private Pf roundtrip for A-frag repack) ----
    short8 qfrag[6];
    #pragma unroll
    for (int nt = 0; nt < 12; ++nt) {
        f32x4 acc = {};
        #pragma unroll
        for (int ks = 0; ks < 6; ++ks) {
            const short8 bfr = *(const short8*)(qkvP + ((nt * 6 + ks) * 64 + lane) * 8);
            acc = __builtin_amdgcn_mfma_f32_16x16x32_bf16(afr[ks], bfr, acc, 0, 0, 0);
        }
        const int hh = nt >> 1, d = ((nt & 1) << 4) + col;
        const float bias = qkv_b[hh * 32 + d];
        #pragma unroll
        for (int r = 0; r < 4; ++r) {
            const int m = rbase + r;
            Pf[wave][((m + (((d >> 3) & 3) << 4)) << 3) + (d & 7)] =
                bf16((acc[r] + bias) * scale);
        }
        if (nt & 1) qfrag[hh] = *(const short8*)&Pf[wave][lane << 3];
    }

    long tok_r[4]; bool iv[4]; int i49[4];
    #pragma unroll
    for (int r = 0; r < 4; ++r) {
        const int i = (wave << 4) + rbase + r;
        iv[r] = i < 49;
        i49[r] = iv[r] ? i * 49 : 0;
        if (iv[r]) {
            const int yi = i / 7, xi = i - yi * 7;
            int h = wh * 7 + yi + 3; if (h >= 56) h -= 56;
            int w = ww * 7 + xi + 3; if (w >= 56) w -= 56;
            tok_r[r] = (long)b * 3136 + h * 56 + w;
        } else tok_r[r] = 0;
    }

    f32x4 oa[12] = {};   // all-head output accumulators [h*2+dt]

    // ---- head loop (UNROLLED: h compile-time -> oa/qfrag statically
    //      indexed -> registers): stage K/V (double-buffered), attend ----
    #pragma unroll
    for (int h = 0; h < 6; ++h) {
        const int bs = h & 1;
        #pragma unroll
        for (int half = 0; half < 2; ++half) {
            const int d = (half << 4) + col;
            // K head h, half
            f32x4 acck = {};
            #pragma unroll
            for (int ks = 0; ks < 6; ++ks) {
                const short8 bfr = *(const short8*)(qkvP +
                    (((12 + 2 * h + half) * 6 + ks) * 64 + lane) * 8);
                acck = __builtin_amdgcn_mfma_f32_16x16x32_bf16(afr[ks], bfr, acck, 0, 0, 0);
            }
            const float biask = qkv_b[192 + h * 32 + d];
            #pragma unroll
            for (int r = 0; r < 4; ++r) {
                const int m = rbase + r;
                Kb[bs][(((wave << 6) + m + (((d >> 3) & 3) << 4)) << 3) + (d & 7)] =
                    bf16(acck[r] + biask);
            }
            // V head h, half
            f32x4 accv = {};
            #pragma unroll
            for (int ks = 0; ks < 6; ++ks) {
                const short8 bfr = *(const short8*)(qkvP +
                    (((24 + 2 * h + half) * 6 + ks) * 64 + lane) * 8);
                accv = __builtin_amdgcn_mfma_f32_16x16x32_bf16(afr[ks], bfr, accv, 0, 0, 0);
            }
            const float biasv = qkv_b[384 + h * 32 + d];
            #pragma unroll
            for (int r = 0; r < 4; ++r) {
                const int m = rbase + r;
                const int flat = ((((half << 1) + (wave >> 1)) << 6) + col +
                                  ((((wave << 1) + (m >> 3)) & 3) << 4)) * 8 + (m & 7);
                Vb[bs][flat] = bf16(accv[r] + biasv);
            }
        }
        __syncthreads();   // K/V(h) visible; also fences attn(h-2) vs this write

        const float* bmp = bm + (((h << 1) + (wh == 7)) * 2 + (ww == 7)) * 2401;
        f32x4 sa[4];
        #pragma unroll
        for (int jt = 0; jt < 4; ++jt) {
            f32x4 z = {};
            const short8 kfr = *(const short8*)&Kb[bs][((jt << 6) + lane) << 3];
            sa[jt] = __builtin_amdgcn_mfma_f32_16x16x32_bf16(qfrag[h], kfr, z, 0, 0, 0);
        }
        float p[4][4];
        #pragma unroll
        for (int jt = 0; jt < 4; ++jt) {
            const int j = (jt << 4) + col;
            #pragma unroll
            for (int r = 0; r < 4; ++r)
                p[jt][r] = (j < 49) ? sa[jt][r] + bmp[i49[r] + j] : -1e30f;
        }
        #pragma unroll
        for (int r = 0; r < 4; ++r) {
            float mx = fmaxf(fmaxf(p[0][r], p[1][r]), fmaxf(p[2][r], p[3][r]));
            mx = fmaxf(mx, __shfl_xor(mx, 1));
            mx = fmaxf(mx, __shfl_xor(mx, 2));
            mx = fmaxf(mx, __shfl_xor(mx, 4));
            mx = fmaxf(mx, __shfl_xor(mx, 8));
            float sum = 0.f;
            #pragma unroll
            for (int jt = 0; jt < 4; ++jt) {
                const float e = (((jt << 4) + col) < 49) ? __expf(p[jt][r] - mx) : 0.f;
                p[jt][r] = e; sum += e;
            }
            sum += __shfl_xor(sum, 1);
            sum += __shfl_xor(sum, 2);
            sum += __shfl_xor(sum, 4);
            sum += __shfl_xor(sum, 8);
            const float inv = 1.0f / sum;
            #pragma unroll
            for (int jt = 0; jt < 4; ++jt) p[jt][r] *= inv;
        }
        #pragma unroll
        for (int jt = 0; jt < 4; ++jt) {
            #pragma unroll
            for (int r = 0; r < 4; ++r) {
                const int m = rbase + r;
                const int flat = (((jt >> 1) << 6) + m +
                                  ((((jt & 1) << 1) + (col >> 3)) << 4)) * 8 + (col & 7);
                Pf[wave][flat] = bf16(p[jt][r]);
            }
        }
        const short8 p0 = *(const short8*)&Pf[wave][lane << 3];
        const short8 p1 = *(const short8*)&Pf[wave][(64 + lane) << 3];
        #pragma unroll
        for (int dt = 0; dt < 2; ++dt) {
            const short8 v0 = *(const short8*)&Vb[bs][(((dt << 1) << 6) + lane) << 3];
            const short8 v1 = *(const short8*)&Vb[bs][((((dt << 1) + 1) << 6) + lane) << 3];
            oa[h * 2 + dt] = __builtin_amdgcn_mfma_f32_16x16x32_bf16(p0, v0, oa[h * 2 + dt], 0, 0, 0);
            oa[h * 2 + dt] = __builtin_amdgcn_mfma_f32_16x16x32_bf16(p1, v1, oa[h * 2 + dt], 0, 0, 0);
        }
    }

    // ---- single contiguous write: 768B per valid token row ----
    #pragma unroll
    for (int r = 0; r < 4; ++r) {
        if (!iv[r]) continue;
        float* op = outp + tok_r[r] * 192;
        #pragma unroll
        for (int hh = 0; hh < 6; ++hh) {
            op[hh * 32 + col]      = oa[hh * 2 + 0][r];
            op[hh * 32 + 16 + col] = oa[hh * 2 + 1][r];
        }
    }
}

// ---------------- fused proj + residual + LN2 + MLP + residual -------------
// Round 16: T4 counted-vmcnt pipeline. 3-buffer ring SB[3][6144]; per phase:
// STAGE chunk p+1 -> s_waitcnt vmcnt(3) (chunk p landed, p+1 in flight) ->
// raw s_barrier -> compute chunk p. Stage at p overwrites buffer read at
// p-2 (safe: all waves passed barrier p-1). One barrier/phase, no vmcnt(0)
// drains in the loop. LDS 40KB -> 4 blocks/CU. Residual in accO (round 12).
__global__ __launch_bounds__(256, 3)
void projmlp_k(const float* attnb, const short* __restrict__ projP,
               const float* __restrict__ pb, const float* __restrict__ x,
               const float* __restrict__ n2g, const float* __restrict__ n2b,
               const short* __restrict__ fc1P, const float* __restrict__ b1,
               const short* __restrict__ fc2P, const float* __restrict__ b2,
               float* outp)
{
    __shared__ __align__(16) short SB[3][6144];  // 12KB-chunk ring (36KB)
    __shared__ __align__(16) short Hs[2048];     // per-wave 512-short H half
    const int tid = threadIdx.x;
    const int wave = tid >> 6, lane = tid & 63;
    const int col = lane & 15, rbase = (lane >> 4) << 2;
    const int kof = (lane >> 4) << 3;
    const long m0 = (long)blockIdx.x * 64;

    // ---- proj phase: A-frags from attnb (wave owns 16 rows) ----
    const long arow = m0 + (wave << 4) + col;
    const float* ap = attnb + arow * 192;
    short8 afr[6];
    #pragma unroll
    for (int ks = 0; ks < 6; ++ks) {
        const int k0 = (ks << 5) + kof;
        const float4 v0 = *(const float4*)(ap + k0);
        const float4 v1 = *(const float4*)(ap + k0 + 4);
        short8 a;
        a[0] = bf16(v0.x); a[1] = bf16(v0.y); a[2] = bf16(v0.z); a[3] = bf16(v0.w);
        a[4] = bf16(v1.x); a[5] = bf16(v1.y); a[6] = bf16(v1.z); a[7] = bf16(v1.w);
        afr[ks] = a;
    }
    f32x4 x1a[12] = {};     // x1 in acc layout; dies before the t-loop
    #pragma unroll
    for (int ks = 0; ks < 6; ++ks) {
        #pragma unroll
        for (int nt = 0; nt < 12; ++nt) {
            const short8 bfr = *(const short8*)(projP + ks * 6144 + (nt << 9) + (lane << 3));
            x1a[nt] = __builtin_amdgcn_mfma_f32_16x16x32_bf16(afr[ks], bfr, x1a[nt], 0, 0, 0);
        }
    }
    // ---- x1 = proj + pb + x (residual), still in registers ----
    const long orow = m0 + (wave << 4) + rbase;   // this lane's 4 output rows
    #pragma unroll
    for (int nt = 0; nt < 12; ++nt) {
        const int n = (nt << 4) + col;
        const float bias = pb[n];
        #pragma unroll
        for (int r = 0; r < 4; ++r)
            x1a[nt][r] += bias + x[(orow + r) * 192 + n];
    }
    // ---- LN2 stats from acc layout (rows rbase..rbase+3, 16 col-lanes) ----
    float s0 = 0.f, s1_ = 0.f, s2_ = 0.f, s3 = 0.f;
    float q0 = 0.f, q1 = 0.f, q2 = 0.f, q3 = 0.f;
    #pragma unroll
    for (int nt = 0; nt < 12; ++nt) {
        s0 += x1a[nt][0]; q0 += x1a[nt][0] * x1a[nt][0];
        s1_ += x1a[nt][1]; q1 += x1a[nt][1] * x1a[nt][1];
        s2_ += x1a[nt][2]; q2 += x1a[nt][2] * x1a[nt][2];
        s3 += x1a[nt][3]; q3 += x1a[nt][3] * x1a[nt][3];
    }
    #pragma unroll
    for (int off = 8; off > 0; off >>= 1) {
        s0 += __shfl_xor(s0, off); q0 += __shfl_xor(q0, off);
        s1_ += __shfl_xor(s1_, off); q1 += __shfl_xor(q1, off);
        s2_ += __shfl_xor(s2_, off); q2 += __shfl_xor(q2, off);
        s3 += __shfl_xor(s3, off); q3 += __shfl_xor(q3, off);
    }
    float mr[4], rr[4];
    mr[0] = s0 * (1.0f / 192.0f); rr[0] = rsqrtf(q0 * (1.0f / 192.0f) - mr[0] * mr[0] + 1e-5f);
    mr[1] = s1_ * (1.0f / 192.0f); rr[1] = rsqrtf(q1 * (1.0f / 192.0f) - mr[1] * mr[1] + 1e-5f);
    mr[2] = s2_ * (1.0f / 192.0f); rr[2] = rsqrtf(q2 * (1.0f / 192.0f) - mr[2] * mr[2] + 1e-5f);
    mr[3] = s3 * (1.0f / 192.0f); rr[3] = rsqrtf(q3 * (1.0f / 192.0f) - mr[3] * mr[3] + 1e-5f);

    // ---- LN2(x1) A-frags -> registers via transient per-wave SB roundtrip --
    short* Xw = (short*)SB + wave * 3072;
    #pragma unroll
    for (int nt = 0; nt < 12; ++nt) {
        const int k = (nt << 4) + col;
        const float g = n2g[k], bb = n2b[k];
        #pragma unroll
        for (int r = 0; r < 4; ++r) {
            const int row16 = rbase + r;
            const int flat = (((k >> 5) << 6) + (((k >> 3) & 3) << 4) + row16) * 8 + (k & 7);
            Xw[flat] = bf16((x1a[nt][r] - mr[r]) * rr[r] * g + bb);
        }
    }
    short8 afrX[6];
    #pragma unroll
    for (int ks = 0; ks < 6; ++ks)
        afrX[ks] = *(const short8*)(Xw + (((ks << 6) + lane) << 3));

    // ---- accO starts at x1 + b2: residual lives in the accumulator ----
    f32x4 accO[12];
    #pragma unroll
    for (int nt = 0; nt < 12; ++nt) {
        const float bias = b2[(nt << 4) + col];
        #pragma unroll
        for (int r = 0; r < 4; ++r)
            accO[nt][r] = x1a[nt][r] + bias;
    }
    // x1a dead from here on.
    __syncthreads();   // all waves done with Xw before staging overwrites SB

    // ---- T4-pipelined MLP loop: ring of 3 buffers, counted vmcnt ----
    auto STAGE = [&](short* dst, const short* src) {
        #pragma unroll
        for (int i = 0; i < 3; ++i) {
            const int slot = (i << 8) + (wave << 6);   // 16B units
            gll16(src + ((slot + lane) << 3), dst + (slot << 3));
        }
    };
    short* Hw = Hs + wave * 512;
    STAGE(&SB[0][0], fc1P);            // chunk 0 (t=0, fc1 h0) -> buf 0
    int rd = 0;                         // ring index of current chunk
    for (int t = 0; t < 12; ++t) {
        const short* f1 = fc1P + t * 12288;
        const short* f2 = fc2P + t * 12288;
        f32x4 accH[4] = {};
        // ---- phase 0: prefetch fc1 h1; GEMM1 nt0,1 from chunk(fc1 h0) ----
        {
            const int wr = (rd == 2) ? 0 : rd + 1;
            STAGE(&SB[wr][0], f1 + 6144);
            asm volatile("s_waitcnt vmcnt(3)" ::: "memory");
            __builtin_amdgcn_s_barrier();
            __builtin_amdgcn_sched_barrier(0);
            const short* B = &SB[rd][0];
            #pragma unroll
            for (int ks = 0; ks < 6; ++ks) {
                #pragma unroll
                for (int ntl = 0; ntl < 2; ++ntl) {
                    const short8 bfr = *(const short8*)&B[((ntl * 6 + ks) << 9) + (lane << 3)];
                    accH[ntl] = __builtin_amdgcn_mfma_f32_16x16x32_bf16(afrX[ks], bfr, accH[ntl], 0, 0, 0);
                }
            }
            rd = wr;
        }
        // ---- phase 1: prefetch fc2 ks0; GEMM1 nt2,3 from chunk(fc1 h1) ----
        {
            const int wr = (rd == 2) ? 0 : rd + 1;
            STAGE(&SB[wr][0], f2);
            asm volatile("s_waitcnt vmcnt(3)" ::: "memory");
            __builtin_amdgcn_s_barrier();
            __builtin_amdgcn_sched_barrier(0);
            const short* B = &SB[rd][0];
            #pragma unroll
            for (int ks = 0; ks < 6; ++ks) {
                #pragma unroll
                for (int ntl = 0; ntl < 2; ++ntl) {
                    const short8 bfr = *(const short8*)&B[((ntl * 6 + ks) << 9) + (lane << 3)];
                    accH[2 + ntl] = __builtin_amdgcn_mfma_f32_16x16x32_bf16(afrX[ks], bfr, accH[2 + ntl], 0, 0, 0);
                }
            }
            rd = wr;
        }
        // ---- phase 2: prefetch fc2 ks1; GELU nt0,1 -> Hw; GEMM2 ks0 ----
        {
            const int wr = (rd == 2) ? 0 : rd + 1;
            STAGE(&SB[wr][0], f2 + 6144);
            asm volatile("s_waitcnt vmcnt(3)" ::: "memory");
            __builtin_amdgcn_s_barrier();
            __builtin_amdgcn_sched_barrier(0);
            const short* B = &SB[rd][0];
            #pragma unroll
            for (int nt = 0; nt < 2; ++nt) {
                const int kh = (nt << 4) + col;
                const float bias = b1[(t << 6) + kh];
                #pragma unroll
                for (int r = 0; r < 4; ++r) {
                    const int m = rbase + r;
                    float val = accH[nt][r] + bias;
                    val = 0.5f * val * (1.0f + erff(val * 0.7071067811865476f));
                    const int flat = ((((kh >> 3) & 3) << 4) + m) * 8 + (kh & 7);
                    Hw[flat] = bf16(val);
                }
            }
            const short8 a = *(const short8*)(Hw + (lane << 3));
            #pragma unroll
            for (int nt2 = 0; nt2 < 12; ++nt2) {
                const short8 bfr = *(const short8*)&B[(nt2 << 9) + (lane << 3)];
                accO[nt2] = __builtin_amdgcn_mfma_f32_16x16x32_bf16(a, bfr, accO[nt2], 0, 0, 0);
            }
            rd = wr;
        }
        // ---- phase 3: prefetch next t fc1 h0; GELU nt2,3 -> Hw; GEMM2 ks1 --
        {
            const int wr = (rd == 2) ? 0 : rd + 1;
            if (t < 11) {
                STAGE(&SB[wr][0], f1 + 12288);
                asm volatile("s_waitcnt vmcnt(3)" ::: "memory");
            } else {
                asm volatile("s_waitcnt vmcnt(0)" ::: "memory");
            }
            __builtin_amdgcn_s_barrier();
            __builtin_amdgcn_sched_barrier(0);
            const short* B = &SB[rd][0];
            #pragma unroll
            for (int nt = 2; nt < 4; ++nt) {
                const int kh = (nt << 4) + col;   // 32..63
                const float bias = b1[(t << 6) + kh];
                #pragma unroll
                for (int r = 0; r < 4; ++r) {
                    const int m = rbase + r;
                    float val = accH[nt][r] + bias;
                    val = 0.5f * val * (1.0f + erff(val * 0.7071067811865476f));
                    const int flat = ((((kh >> 3) & 3) << 4) + m) * 8 + (kh & 7);
                    Hw[flat] = bf16(val);
                }
            }
            const short8 a = *(const short8*)(Hw + (lane << 3));
            #pragma unroll
            for (int nt2 = 0; nt2 < 12; ++nt2) {
                const short8 bfr = *(const short8*)&B[(nt2 << 9) + (lane << 3)];
                accO[nt2] = __builtin_amdgcn_mfma_f32_16x16x32_bf16(a, bfr, accO[nt2], 0, 0, 0);
            }
            rd = wr;
        }
    }

    // ---- epilogue: out = accO (x1 + b2 + mlp already accumulated) ----
    #pragma unroll
    for (int nt = 0; nt < 12; ++nt) {
        const int n = (nt << 4) + col;
        #pragma unroll
        for (int r = 0; r < 4; ++r)
            outp[(orow + r) * 192 + n] = accO[nt][r];
    }
}

// ---------------------------------------------------------------------------
extern "C" void kernel_launch(void* const* d_in, const int* in_sizes, int n_in,
                              void* d_out, int out_size, void* d_ws, size_t ws_size,
                              hipStream_t stream)
{
    const float* x      = (const float*)d_in[0];
    const float* n1g    = (const float*)d_in[1];
    const float* n1b    = (const float*)d_in[2];
    const float* qkv_w  = (const float*)d_in[3];
    const float* qkv_b  = (const float*)d_in[4];
    const float* relb   = (const float*)d_in[5];
    const float* proj_w = (const float*)d_in[6];
    const float* proj_b = (const float*)d_in[7];
    const float* n2g    = (const float*)d_in[8];
    const float* n2b    = (const float*)d_in[9];
    const float* fc1_w  = (const float*)d_in[10];
    const float* fc1_b  = (const float*)d_in[11];
    const float* fc2_w  = (const float*)d_in[12];
    const float* fc2_b  = (const float*)d_in[13];
    float* out = (float*)d_out;
    char*  ws  = (char*)d_ws;

    float* mb    = (float*)(ws);                   //   401,408 B
    float* rb    = (float*)(ws +   401408L);       //   401,408 B
    short* qkvP  = (short*)(ws +   802816L);       //   221,184 B
    short* projP = (short*)(ws +  1024000L);       //    73,728 B
    short* fc1P  = (short*)(ws +  1097728L);       //   294,912 B
    short* fc2P  = (short*)(ws +  1392640L);       //   294,912 B
    float* bmT   = (float*)(ws +  1687552L);       //   230,496 B  (~1.92 MB total)

    // 1) all prep (packs, bias table, LN1 stats) in one launch
    prep_k<<<1954 + T / 4, 256, 0, stream>>>(qkv_w, proj_w, fc1_w, fc2_w,
                                             relb, x, qkvP, projP, fc1P,
                                             fc2P, bmT, mb, rb);
    // 2) fused LN1+shift+window+QKV+MFMA attention -> d_out (natural order)
    winattn_k<<<2048, 256, 0, stream>>>(x, n1g, n1b, qkvP, qkv_b,
                                        bmT, mb, rb, out);
    // 3+4) fused: out = x1 + GELU(LN2(x1)@fc1+b1)@fc2+b2,
    //      x1 = attn@proj_w+pb+x kept in registers (never hits HBM)
    projmlp_k<<<T / 64, 256, 0, stream>>>(out, projP, proj_b, x, n2g, n2b,
                                          fc1P, fc1_b, fc2P, fc2_b, out);
}

// Round 11
// 451.638 us; speedup vs baseline: 1.0352x; 1.0352x over previous
//
#include <hip/hip_runtime.h>
#include <math.h>

// ---------------------------------------------------------------------------
// Swin block, bf16-MFMA, MI355X. B=32 H=W=56 C=192 NH=6 hd=32 WS=7 SS=3.
// T=100352. GEMMs: 16x16x32 bf16 MFMA, fp32 accum. LN/softmax/GELU/residual
// in fp32. Weights repacked per-launch into MFMA B-fragment order (bf16).
// Round 17: rounds 15/16 proved phase-split pipelining loses to round-14's
// simple 2-barrier/t loop (barrier-skew cost >= overlap gain). Revert to
// that structure and scale the block instead: 512 threads / 8 waves / 128
// rows per block. Per-t staging (48KB from L2) now serves 2x rows (half the
// per-row staging + drains); LDS 56KB (Xf roundtrip borrows S1+S2, Hs 8KB)
// -> 2 blocks/CU = 16 waves/CU (50% cap, was ~8). Same per-thread register
// footprint (~80 VGPR < 128 cap of (512,4)) -> no spill.
// ---------------------------------------------------------------------------

constexpr long T = 100352;

typedef __attribute__((ext_vector_type(8))) short short8;   // 8 bf16
typedef __attribute__((ext_vector_type(4))) float f32x4;    // MFMA acc

__device__ __forceinline__ short bf16(float f) {
    union { float f; unsigned u; } v; v.f = f;
    return (short)((v.u + 0x7fff + ((v.u >> 16) & 1)) >> 16);
}

__device__ __forceinline__ void gll16(const void* g, void* l) {
    __builtin_amdgcn_global_load_lds(
        (const __attribute__((address_space(1))) void*)g,
        (__attribute__((address_space(3))) void*)l, 16, 0, 0);
}

// ---------------- merged prep: packs + bias table + LN1 stats --------------
// bid <  432 : qkv pack (K=192,N=576)
// bid <  576 : proj pack (K=192,N=192, [ks][nt])
// bid < 1152 : fc1 pack (K=192,N=768)
// bid < 1728 : fc2 pack (K=768,N=192, [t][ks][nt] -- ks-halves contiguous)
// bid < 1954 : rel-pos-bias + shift-mask table
// else       : LN1 per-token stats (4 tokens/block)
__global__ __launch_bounds__(256)
void prep_k(const float* __restrict__ qkv_w, const float* __restrict__ proj_w,
            const float* __restrict__ fc1_w, const float* __restrict__ fc2_w,
            const float* __restrict__ relb, const float* __restrict__ x,
            short* __restrict__ qkvP, short* __restrict__ projP,
            short* __restrict__ fc1P, short* __restrict__ fc2P,
            float* __restrict__ bm, float* __restrict__ mean,
            float* __restrict__ rstd)
{
    const int bid = blockIdx.x;
    const int tid = threadIdx.x;
    if (bid < 432) {                    // qkv
        const int idx = bid * 256 + tid;
        const int k = idx / 576, n = idx - k * 576;
        const int flat = (((n >> 4) * 6 + (k >> 5)) * 64 +
                          (((k >> 3) & 3) << 4) + (n & 15)) * 8 + (k & 7);
        qkvP[flat] = bf16(qkv_w[idx]);
    } else if (bid < 576) {             // proj
        const int idx = (bid - 432) * 256 + tid;
        const int k = idx / 192, n = idx - k * 192;
        const int flat = ((((k >> 5) * 12 + (n >> 4)) * 64) +
                          (((k >> 3) & 3) << 4) + (n & 15)) * 8 + (k & 7);
        projP[flat] = bf16(proj_w[idx]);
    } else if (bid < 1152) {            // fc1
        const int idx = (bid - 576) * 256 + tid;
        const int k = idx / 768, n = idx - k * 768;
        const int flat = (((n >> 4) * 6 + (k >> 5)) * 64 +
                          (((k >> 3) & 3) << 4) + (n & 15)) * 8 + (k & 7);
        fc1P[flat] = bf16(fc1_w[idx]);
    } else if (bid < 1728) {            // fc2 [t][ks][nt]
        const int idx = (bid - 1152) * 256 + tid;
        const int k = idx / 192, n = idx - k * 192;
        const int t = k >> 6, ks = (k >> 5) & 1, nt = n >> 4;
        const int flat = (((t * 2 + ks) * 12 + nt) * 64 +
                          (((k >> 3) & 3) << 4) + (n & 15)) * 8 + (k & 7);
        fc2P[flat] = bf16(fc2_w[idx]);
    } else if (bid < 1954) {            // bias+mask table
        const int idx = (bid - 1728) * 256 + tid;
        if (idx >= 6 * 4 * 2401) return;
        const int e = idx % 2401, rest = idx / 2401;
        const int tw = rest & 1, th = (rest >> 1) & 1, head = rest >> 2;
        const int i = e / 49, j = e - i * 49;
        const int yi = i / 7, xi = i - yi * 7, yj = j / 7, xj = j - yj * 7;
        const float v = relb[((yi - yj + 6) * 13 + (xi - xj + 6)) * 6 + head];
        const int hi = th ? 49 + yi : yi, hj = th ? 49 + yj : yj;
        const int wa = tw ? 49 + xi : xi, wb = tw ? 49 + xj : xj;
        const int Li = (hi < 49 ? 0 : (hi < 53 ? 1 : 2)) * 3 + (wa < 49 ? 0 : (wa < 53 ? 1 : 2));
        const int Lj = (hj < 49 ? 0 : (hj < 53 ? 1 : 2)) * 3 + (wb < 49 ? 0 : (wb < 53 ? 1 : 2));
        bm[idx] = (Li != Lj) ? v - 100.0f : v;
    } else {                            // LN1 stats
        const int wave = tid >> 6;
        const int lane = tid & 63;
        const long tok = (long)(bid - 1954) * 4 + wave;
        const float* p = x + tok * 192;
        const float a = p[lane], b = p[lane + 64], c = p[lane + 128];
        float s = a + b + c;
        float q = a * a + b * b + c * c;
        #pragma unroll
        for (int off = 32; off > 0; off >>= 1) {
            s += __shfl_xor(s, off);
            q += __shfl_xor(q, off);
        }
        if (lane == 0) {
            const float m = s * (1.0f / 192.0f);
            const float v = q * (1.0f / 192.0f) - m * m;
            mean[tok] = m;
            rstd[tok] = 1.0f / sqrtf(v + 1e-5f);
        }
    }
}

// ---------------- fused LN1+shift+window+QKV+MFMA attention ----------------
// (round 14: head loop fully unrolled so oa[]/qfrag[] are statically indexed;
// per-head double-buffered K/V, LDS 24KB, single 768B row write at end)
__global__ __launch_bounds__(256, 3)
void winattn_k(const float* __restrict__ x, const float* __restrict__ n1g,
               const float* __restrict__ n1b, const short* __restrict__ qkvP,
               const float* __restrict__ qkv_b, const float* __restrict__ bm,
               const float* __restrict__ mean, const float* __restrict__ rstd,
               float* __restrict__ outp)
{
    __shared__ __align__(16) short Kb[2][2048];
    __shared__ __align__(16) short Vb[2][2048];
    __shared__ __align__(16) short Pf[4][1024];
    const int bw  = blockIdx.x;
    const int tid = threadIdx.x;
    const int b = bw >> 6, wi = bw & 63, wh = wi >> 3, ww = wi & 7;
    const int wave = tid >> 6, lane = tid & 63;
    const int col = lane & 15, rbase = (lane >> 4) << 2;
    const float scale = 0.17677669529663687f;

    const int am = lane & 15;
    const int arow = (wave << 4) + am;
    const int kof = (lane >> 4) << 3;
    short8 afr[6];
    long tokA = 0; float mA = 0.f, rsA = 1.f;
    const bool avalid = arow < 49;
    if (avalid) {
        const int yi = arow / 7, xi = arow - yi * 7;
        int h = wh * 7 + yi + 3; if (h >= 56) h -= 56;
        int w = ww * 7 + xi + 3; if (w >= 56) w -= 56;
        tokA = (long)b * 3136 + h * 56 + w;
        mA = mean[tokA]; rsA = rstd[tokA];
    }
    #pragma unroll
    for (int ks = 0; ks < 6; ++ks) {
        short8 a = {};
        if (avalid) {
            const int k0 = (ks << 5) + kof;
            const float4 v0 = *(const float4*)(x + tokA * 192 + k0);
            const float4 v1 = *(const float4*)(x + tokA * 192 + k0 + 4);
            const float4 g0 = *(const float4*)(n1g + k0);
            const float4 g1 = *(const float4*)(n1g + k0 + 4);
            const float4 e0 = *(const float4*)(n1b + k0);
            const float4 e1 = *(const float4*)(n1b + k0 + 4);
            a[0] = bf16((v0.x - mA) * rsA * g0.x + e0.x);
            a[1] = bf16((v0.y - mA) * rsA * g0.y + e0.y);
            a[2] = bf16((v0.z - mA) * rsA * g0.z + e0.z);
            a[3] = bf16((v0.w - mA) * rsA * g0.w + e0.w);
            a[4] = bf16((v1.x - mA) * rsA * g1.x + e1.x);
            a[5] = bf16((v1.y - mA) * rsA * g1.y + e1.y);
            a[6] = bf16((v1.z - mA) * rsA * g1.z + e1.z);
            a[7] = bf16((v1.w - mA) * rsA * g1.w + e1.w);
        }
        afr[ks] = a;
    }

    // ---- Q for all heads (wave-private Pf roundtrip for A-frag repack) ----
    short8 qfrag[6];
    #pragma unroll
    for (int nt = 0; nt < 12; ++nt) {
        f32x4 acc = {};
        #pragma unroll
        for (int ks = 0; ks < 6; ++ks) {
            const short8 bfr = *(const short8*)(qkvP + ((nt * 6 + ks) * 64 + lane) * 8);
            acc = __builtin_amdgcn_mfma_f32_16x16x32_bf16(afr[ks], bfr, acc, 0, 0, 0);
        }
        const int hh = nt >> 1, d = ((nt & 1) << 4) + col;
        const float bias = qkv_b[hh * 32 + d];
        #pragma unroll
        for (int r = 0; r < 4; ++r) {
            const int m = rbase + r;
            Pf[wave][((m + (((d >> 3) & 3) << 4)) << 3) + (d & 7)] =
                bf16((acc[r] + bias) * scale);
        }
        if (nt & 1) qfrag[hh] = *(const short8*)&Pf[wave][lane << 3];
    }

    long tok_r[4]; bool iv[4]; int i49[4];
    #pragma unroll
    for (int r = 0; r < 4; ++r) {
        const int i = (wave << 4) + rbase + r;
        iv[r] = i < 49;
        i49[r] = iv[r] ? i * 49 : 0;
        if (iv[r]) {
            const int yi = i / 7, xi = i - yi * 7;
            int h = wh * 7 + yi + 3; if (h >= 56) h -= 56;
            int w = ww * 7 + xi + 3; if (w >= 56) w -= 56;
            tok_r[r] = (long)b * 3136 + h * 56 + w;
        } else tok_r[r] = 0;
    }

    f32x4 oa[12] = {};   // all-head output accumulators [h*2+dt]

    // ---- head loop (UNROLLED: h compile-time -> oa/qfrag statically
    //      indexed -> registers): stage K/V (double-buffered), attend ----
    #pragma unroll
    for (int h = 0; h < 6; ++h) {
        const int bs = h & 1;
        #pragma unroll
        for (int half = 0; half < 2; ++half) {
            const int d = (half << 4) + col;
            // K head h, half
            f32x4 acck = {};
            #pragma unroll
            for (int ks = 0; ks < 6; ++ks) {
                const short8 bfr = *(const short8*)(qkvP +
                    (((12 + 2 * h + half) * 6 + ks) * 64 + lane) * 8);
                acck = __builtin_amdgcn_mfma_f32_16x16x32_bf16(afr[ks], bfr, acck, 0, 0, 0);
            }
            const float biask = qkv_b[192 + h * 32 + d];
            #pragma unroll
            for (int r = 0; r < 4; ++r) {
                const int m = rbase + r;
                Kb[bs][(((wave << 6) + m + (((d >> 3) & 3) << 4)) << 3) + (d & 7)] =
                    bf16(acck[r] + biask);
            }
            // V head h, half
            f32x4 accv = {};
            #pragma unroll
            for (int ks = 0; ks < 6; ++ks) {
                const short8 bfr = *(const short8*)(qkvP +
                    (((24 + 2 * h + half) * 6 + ks) * 64 + lane) * 8);
                accv = __builtin_amdgcn_mfma_f32_16x16x32_bf16(afr[ks], bfr, accv, 0, 0, 0);
            }
            const float biasv = qkv_b[384 + h * 32 + d];
            #pragma unroll
            for (int r = 0; r < 4; ++r) {
                const int m = rbase + r;
                const int flat = ((((half << 1) + (wave >> 1)) << 6) + col +
                                  ((((wave << 1) + (m >> 3)) & 3) << 4)) * 8 + (m & 7);
                Vb[bs][flat] = bf16(accv[r] + biasv);
            }
        }
        __syncthreads();   // K/V(h) visible; also fences attn(h-2) vs this write

        const float* bmp = bm + (((h << 1) + (wh == 7)) * 2 + (ww == 7)) * 2401;
        f32x4 sa[4];
        #pragma unroll
        for (int jt = 0; jt < 4; ++jt) {
            f32x4 z = {};
            const short8 kfr = *(const short8*)&Kb[bs][((jt << 6) + lane) << 3];
            sa[jt] = __builtin_amdgcn_mfma_f32_16x16x32_bf16(qfrag[h], kfr, z, 0, 0, 0);
        }
        float p[4][4];
        #pragma unroll
        for (int jt = 0; jt < 4; ++jt) {
            const int j = (jt << 4) + col;
            #pragma unroll
            for (int r = 0; r < 4; ++r)
                p[jt][r] = (j < 49) ? sa[jt][r] + bmp[i49[r] + j] : -1e30f;
        }
        #pragma unroll
        for (int r = 0; r < 4; ++r) {
            float mx = fmaxf(fmaxf(p[0][r], p[1][r]), fmaxf(p[2][r], p[3][r]));
            mx = fmaxf(mx, __shfl_xor(mx, 1));
            mx = fmaxf(mx, __shfl_xor(mx, 2));
            mx = fmaxf(mx, __shfl_xor(mx, 4));
            mx = fmaxf(mx, __shfl_xor(mx, 8));
            float sum = 0.f;
            #pragma unroll
            for (int jt = 0; jt < 4; ++jt) {
                const float e = (((jt << 4) + col) < 49) ? __expf(p[jt][r] - mx) : 0.f;
                p[jt][r] = e; sum += e;
            }
            sum += __shfl_xor(sum, 1);
            sum += __shfl_xor(sum, 2);
            sum += __shfl_xor(sum, 4);
            sum += __shfl_xor(sum, 8);
            const float inv = 1.0f / sum;
            #pragma unroll
            for (int jt = 0; jt < 4; ++jt) p[jt][r] *= inv;
        }
        #pragma unroll
        for (int jt = 0; jt < 4; ++jt) {
            #pragma unroll
            for (int r = 0; r < 4; ++r) {
                const int m = rbase + r;
                const int flat = (((jt >> 1) << 6) + m +
                                  ((((jt & 1) << 1) + (col >> 3)) << 4)) * 8 + (col & 7);
                Pf[wave][flat] = bf16(p[jt][r]);
            }
        }
        const short8 p0 = *(const short8*)&Pf[wave][lane << 3];
        const short8 p1 = *(const short8*)&Pf[wave][(64 + lane) << 3];
        #pragma unroll
        for (int dt = 0; dt < 2; ++dt) {
            const short8 v0 = *(const short8*)&Vb[bs][(((dt << 1) << 6) + lane) << 3];
            const short8 v1 = *(const short8*)&Vb[bs][((((dt << 1) + 1) << 6) + lane) << 3];
            oa[h * 2 + dt] = __builtin_amdgcn_mfma_f32_16x16x32_bf16(p0, v0, oa[h * 2 + dt], 0, 0, 0);
            oa[h * 2 + dt] = __builtin_amdgcn_mfma_f32_16x16x32_bf16(p1, v1, oa[h * 2 + dt], 0, 0, 0);
        }
    }

    // ---- single contiguous write: 768B per valid token row ----
    #pragma unroll
    for (int r = 0; r < 4; ++r) {
        if (!iv[r]) continue;
        float* op = outp + tok_r[r] * 192;
        #pragma unroll
        for (int hh = 0; hh < 6; ++hh) {
            op[hh * 32 + col]      = oa[hh * 2 + 0][r];
            op[hh * 32 + 16 + col] = oa[hh * 2 + 1][r];
        }
    }
}

// ---------------- fused proj + residual + LN2 + MLP + residual -------------
// Round 17: 512 threads / 8 waves / 128 rows per block; round-14 t-loop
// (stage full 48KB tile pair via gll16, 2 barriers per t). Xf roundtrip
// borrows S1(waves 0-3)+S2(waves 4-7). GEMM2 reads S2 in [ks][nt] order.
// LDS 56KB -> 2 blocks/CU = 16 waves/CU. Residual folded into accO.
__global__ __launch_bounds__(512, 4)
void projmlp_k(const float* attnb, const short* __restrict__ projP,
               const float* __restrict__ pb, const float* __restrict__ x,
               const float* __restrict__ n2g, const float* __restrict__ n2b,
               const short* __restrict__ fc1P, const float* __restrict__ b1,
               const short* __restrict__ fc2P, const float* __restrict__ b2,
               float* outp)
{
    __shared__ __align__(16) short S1[12288];   // fc1 t-tile (24KB)
    __shared__ __align__(16) short S2[12288];   // fc2 t-tile (24KB)
    __shared__ __align__(16) short Hs[4096];    // 8 waves x 512-short H half
    const int tid = threadIdx.x;
    const int wave = tid >> 6, lane = tid & 63;
    const int col = lane & 15, rbase = (lane >> 4) << 2;
    const int kof = (lane >> 4) << 3;
    const long m0 = (long)blockIdx.x * 128;

    // ---- proj phase: A-frags from attnb (each wave owns 16 rows) ----
    const long arow = m0 + (wave << 4) + col;
    const float* ap = attnb + arow * 192;
    short8 afr[6];
    #pragma unroll
    for (int ks = 0; ks < 6; ++ks) {
        const int k0 = (ks << 5) + kof;
        const float4 v0 = *(const float4*)(ap + k0);
        const float4 v1 = *(const float4*)(ap + k0 + 4);
        short8 a;
        a[0] = bf16(v0.x); a[1] = bf16(v0.y); a[2] = bf16(v0.z); a[3] = bf16(v0.w);
        a[4] = bf16(v1.x); a[5] = bf16(v1.y); a[6] = bf16(v1.z); a[7] = bf16(v1.w);
        afr[ks] = a;
    }
    f32x4 x1a[12] = {};     // x1 in acc layout; dies before the t-loop
    #pragma unroll
    for (int ks = 0; ks < 6; ++ks) {
        #pragma unroll
        for (int nt = 0; nt < 12; ++nt) {
            const short8 bfr = *(const short8*)(projP + ks * 6144 + (nt << 9) + (lane << 3));
            x1a[nt] = __builtin_amdgcn_mfma_f32_16x16x32_bf16(afr[ks], bfr, x1a[nt], 0, 0, 0);
        }
    }
    // ---- x1 = proj + pb + x (residual), still in registers ----
    const long orow = m0 + (wave << 4) + rbase;   // this lane's 4 output rows
    #pragma unroll
    for (int nt = 0; nt < 12; ++nt) {
        const int n = (nt << 4) + col;
        const float bias = pb[n];
        #pragma unroll
        for (int r = 0; r < 4; ++r)
            x1a[nt][r] += bias + x[(orow + r) * 192 + n];
    }
    // ---- LN2 stats from acc layout (rows rbase..rbase+3, 16 col-lanes) ----
    float s0 = 0.f, s1_ = 0.f, s2_ = 0.f, s3 = 0.f;
    float q0 = 0.f, q1 = 0.f, q2 = 0.f, q3 = 0.f;
    #pragma unroll
    for (int nt = 0; nt < 12; ++nt) {
        s0 += x1a[nt][0]; q0 += x1a[nt][0] * x1a[nt][0];
        s1_ += x1a[nt][1]; q1 += x1a[nt][1] * x1a[nt][1];
        s2_ += x1a[nt][2]; q2 += x1a[nt][2] * x1a[nt][2];
        s3 += x1a[nt][3]; q3 += x1a[nt][3] * x1a[nt][3];
    }
    #pragma unroll
    for (int off = 8; off > 0; off >>= 1) {
        s0 += __shfl_xor(s0, off); q0 += __shfl_xor(q0, off);
        s1_ += __shfl_xor(s1_, off); q1 += __shfl_xor(q1, off);
        s2_ += __shfl_xor(s2_, off); q2 += __shfl_xor(q2, off);
        s3 += __shfl_xor(s3, off); q3 += __shfl_xor(q3, off);
    }
    float mr[4], rr[4];
    mr[0] = s0 * (1.0f / 192.0f); rr[0] = rsqrtf(q0 * (1.0f / 192.0f) - mr[0] * mr[0] + 1e-5f);
    mr[1] = s1_ * (1.0f / 192.0f); rr[1] = rsqrtf(q1 * (1.0f / 192.0f) - mr[1] * mr[1] + 1e-5f);
    mr[2] = s2_ * (1.0f / 192.0f); rr[2] = rsqrtf(q2 * (1.0f / 192.0f) - mr[2] * mr[2] + 1e-5f);
    mr[3] = s3 * (1.0f / 192.0f); rr[3] = rsqrtf(q3 * (1.0f / 192.0f) - mr[3] * mr[3] + 1e-5f);

    // ---- LN2(x1) A-frags -> registers via transient roundtrip:
    //      waves 0-3 use S1, waves 4-7 use S2 (both free before t-loop) ----
    short* Xw = (wave < 4 ? S1 : S2) + (wave & 3) * 3072;
    #pragma unroll
    for (int nt = 0; nt < 12; ++nt) {
        const int k = (nt << 4) + col;
        const float g = n2g[k], bb = n2b[k];
        #pragma unroll
        for (int r = 0; r < 4; ++r) {
            const int row16 = rbase + r;
            const int flat = (((k >> 5) << 6) + (((k >> 3) & 3) << 4) + row16) * 8 + (k & 7);
            Xw[flat] = bf16((x1a[nt][r] - mr[r]) * rr[r] * g + bb);
        }
    }
    short8 afrX[6];
    #pragma unroll
    for (int ks = 0; ks < 6; ++ks)
        afrX[ks] = *(const short8*)(Xw + (((ks << 6) + lane) << 3));

    // ---- accO starts at x1 + b2: residual lives in the accumulator ----
    f32x4 accO[12];
    #pragma unroll
    for (int nt = 0; nt < 12; ++nt) {
        const float bias = b2[(nt << 4) + col];
        #pragma unroll
        for (int r = 0; r < 4; ++r)
            accO[nt][r] = x1a[nt][r] + bias;
    }
    // x1a dead from here on.

    // ---- MLP loop (round-14 structure): stage full tile pair, 2 barriers --
    short* Hw = Hs + wave * 512;
    for (int t = 0; t < 12; ++t) {
        __syncthreads();               // all waves done reading S (or Xw)
        {
            const short* f1 = fc1P + t * 12288;
            const short* f2 = fc2P + t * 12288;
            #pragma unroll
            for (int i = 0; i < 3; ++i) {   // 512 threads x 3 slots x 16B = 24KB
                const int slot = (i << 9) + tid;   // 16B units
                gll16(f1 + (slot << 3), S1 + (slot << 3));
                gll16(f2 + (slot << 3), S2 + (slot << 3));
            }
        }
        __syncthreads();               // drains vmcnt -> tiles visible
        // GEMM1: H(16x64 per wave) = afrX @ fc1_tile
        f32x4 accH[4] = {};
        #pragma unroll
        for (int ks = 0; ks < 6; ++ks) {
            #pragma unroll
            for (int nt = 0; nt < 4; ++nt) {
                const short8 bfr = *(const short8*)&S1[((nt * 6 + ks) << 9) + (lane << 3)];
                accH[nt] = __builtin_amdgcn_mfma_f32_16x16x32_bf16(afrX[ks], bfr, accH[nt], 0, 0, 0);
            }
        }
        // bias + exact GELU -> Hw half-slices; GEMM2 per half (wave-private)
        #pragma unroll
        for (int hf = 0; hf < 2; ++hf) {
            #pragma unroll
            for (int ntl = 0; ntl < 2; ++ntl) {
                const int nt = (hf << 1) + ntl;
                const int kh = (nt << 4) + col;
                const float bias = b1[(t << 6) + kh];
                #pragma unroll
                for (int r = 0; r < 4; ++r) {
                    const int m = rbase + r;
                    float val = accH[nt][r] + bias;
                    val = 0.5f * val * (1.0f + erff(val * 0.7071067811865476f));
                    const int flat = ((((kh >> 3) & 3) << 4) + m) * 8 + (kh & 7);
                    Hw[flat] = bf16(val);
                }
            }
            const short8 a = *(const short8*)(Hw + (lane << 3));
            #pragma unroll
            for (int nt2 = 0; nt2 < 12; ++nt2) {   // S2 is [ks][nt] packed
                const short8 bfr = *(const short8*)&S2[((hf * 12 + nt2) << 9) + (lane << 3)];
                accO[nt2] = __builtin_amdgcn_mfma_f32_16x16x32_bf16(a, bfr, accO[nt2], 0, 0, 0);
            }
        }
    }

    // ---- epilogue: out = accO (x1 + b2 + mlp already accumulated) ----
    #pragma unroll
    for (int nt = 0; nt < 12; ++nt) {
        const int n = (nt << 4) + col;
        #pragma unroll
        for (int r = 0; r < 4; ++r)
            outp[(orow + r) * 192 + n] = accO[nt][r];
    }
}

// ---------------------------------------------------------------------------
extern "C" void kernel_launch(void* const* d_in, const int* in_sizes, int n_in,
                              void* d_out, int out_size, void* d_ws, size_t ws_size,
                              hipStream_t stream)
{
    const float* x      = (const float*)d_in[0];
    const float* n1g    = (const float*)d_in[1];
    const float* n1b    = (const float*)d_in[2];
    const float* qkv_w  = (const float*)d_in[3];
    const float* qkv_b  = (const float*)d_in[4];
    const float* relb   = (const float*)d_in[5];
    const float* proj_w = (const float*)d_in[6];
    const float* proj_b = (const float*)d_in[7];
    const float* n2g    = (const float*)d_in[8];
    const float* n2b    = (const float*)d_in[9];
    const float* fc1_w  = (const float*)d_in[10];
    const float* fc1_b  = (const float*)d_in[11];
    const float* fc2_w  = (const float*)d_in[12];
    const float* fc2_b  = (const float*)d_in[13];
    float* out = (float*)d_out;
    char*  ws  = (char*)d_ws;

    float* mb    = (float*)(ws);                   //   401,408 B
    float* rb    = (float*)(ws +   401408L);       //   401,408 B
    short* qkvP  = (short*)(ws +   802816L);       //   221,184 B
    short* projP = (short*)(ws +  1024000L);       //    73,728 B
    short* fc1P  = (short*)(ws +  1097728L);       //   294,912 B
    short* fc2P  = (short*)(ws +  1392640L);       //   294,912 B
    float* bmT   = (float*)(ws +  1687552L);       //   230,496 B  (~1.92 MB total)

    // 1) all prep (packs, bias table, LN1 stats) in one launch
    prep_k<<<1954 + T / 4, 256, 0, stream>>>(qkv_w, proj_w, fc1_w, fc2_w,
                                             relb, x, qkvP, projP, fc1P,
                                             fc2P, bmT, mb, rb);
    // 2) fused LN1+shift+window+QKV+MFMA attention -> d_out (natural order)
    winattn_k<<<2048, 256, 0, stream>>>(x, n1g, n1b, qkvP, qkv_b,
                                        bmT, mb, rb, out);
    // 3+4) fused: out = x1 + GELU(LN2(x1)@fc1+b1)@fc2+b2,
    //      x1 = attn@proj_w+pb+x kept in registers (never hits HBM)
    projmlp_k<<<T / 128, 512, 0, stream>>>(out, projP, proj_b, x, n2g, n2b,
                                           fc1P, fc1_b, fc2P, fc2_b, out);
}

// Round 12
// 447.499 us; speedup vs baseline: 1.0447x; 1.0092x over previous
//
#include <hip/hip_runtime.h>
#include <math.h>

// ---------------------------------------------------------------------------
// Swin block, bf16-MFMA, MI355X. B=32 H=W=56 C=192 NH=6 hd=32 WS=7 SS=3.
// T=100352. GEMMs: 16x16x32 bf16 MFMA, fp32 accum. LN/softmax/GELU/residual
// in fp32. Weights repacked per-launch into MFMA B-fragment order (bf16).
// Round 18: FULL FUSION winattn+projmlp -> winfull_k. The attn output
// (oa[12], full 192-ch row in C-layout) is repacked in-register to proj
// A-frags via the PROVEN Q-phase Pf roundtrip (6x), proj runs from regs
// (+x residual via tok_r), LN2 in-register, then the round-14/17 MLP
// t-loop. 77MB write + 77MB read of the attn intermediate disappear, and
// one kernel launch goes away. LDS phase-aliased union 52KB:
// [Kb 8K|Vb 8K|Pf 8K] -> [Xw 24K] -> [S1 24K][S2 24K][Hs 4K], barriers at
// phase transitions. MLP per-window (49/64 valid rows, +23% MFMA waste --
// cheap vs the serialization/traffic removed).
// ---------------------------------------------------------------------------

constexpr long T = 100352;

typedef __attribute__((ext_vector_type(8))) short short8;   // 8 bf16
typedef __attribute__((ext_vector_type(4))) float f32x4;    // MFMA acc

__device__ __forceinline__ short bf16(float f) {
    union { float f; unsigned u; } v; v.f = f;
    return (short)((v.u + 0x7fff + ((v.u >> 16) & 1)) >> 16);
}

__device__ __forceinline__ void gll16(const void* g, void* l) {
    __builtin_amdgcn_global_load_lds(
        (const __attribute__((address_space(1))) void*)g,
        (__attribute__((address_space(3))) void*)l, 16, 0, 0);
}

// ---------------- merged prep: packs + bias table + LN1 stats --------------
// bid <  432 : qkv pack (K=192,N=576)
// bid <  576 : proj pack (K=192,N=192, [ks][nt])
// bid < 1152 : fc1 pack (K=192,N=768)
// bid < 1728 : fc2 pack (K=768,N=192, [t][ks][nt] -- ks-halves contiguous)
// bid < 1954 : rel-pos-bias + shift-mask table
// else       : LN1 per-token stats (4 tokens/block)
__global__ __launch_bounds__(256)
void prep_k(const float* __restrict__ qkv_w, const float* __restrict__ proj_w,
            const float* __restrict__ fc1_w, const float* __restrict__ fc2_w,
            const float* __restrict__ relb, const float* __restrict__ x,
            short* __restrict__ qkvP, short* __restrict__ projP,
            short* __restrict__ fc1P, short* __restrict__ fc2P,
            float* __restrict__ bm, float* __restrict__ mean,
            float* __restrict__ rstd)
{
    const int bid = blockIdx.x;
    const int tid = threadIdx.x;
    if (bid < 432) {                    // qkv
        const int idx = bid * 256 + tid;
        const int k = idx / 576, n = idx - k * 576;
        const int flat = (((n >> 4) * 6 + (k >> 5)) * 64 +
                          (((k >> 3) & 3) << 4) + (n & 15)) * 8 + (k & 7);
        qkvP[flat] = bf16(qkv_w[idx]);
    } else if (bid < 576) {             // proj
        const int idx = (bid - 432) * 256 + tid;
        const int k = idx / 192, n = idx - k * 192;
        const int flat = ((((k >> 5) * 12 + (n >> 4)) * 64) +
                          (((k >> 3) & 3) << 4) + (n & 15)) * 8 + (k & 7);
        projP[flat] = bf16(proj_w[idx]);
    } else if (bid < 1152) {            // fc1
        const int idx = (bid - 576) * 256 + tid;
        const int k = idx / 768, n = idx - k * 768;
        const int flat = (((n >> 4) * 6 + (k >> 5)) * 64 +
                          (((k >> 3) & 3) << 4) + (n & 15)) * 8 + (k & 7);
        fc1P[flat] = bf16(fc1_w[idx]);
    } else if (bid < 1728) {            // fc2 [t][ks][nt]
        const int idx = (bid - 1152) * 256 + tid;
        const int k = idx / 192, n = idx - k * 192;
        const int t = k >> 6, ks = (k >> 5) & 1, nt = n >> 4;
        const int flat = (((t * 2 + ks) * 12 + nt) * 64 +
                          (((k >> 3) & 3) << 4) + (n & 15)) * 8 + (k & 7);
        fc2P[flat] = bf16(fc2_w[idx]);
    } else if (bid < 1954) {            // bias+mask table
        const int idx = (bid - 1728) * 256 + tid;
        if (idx >= 6 * 4 * 2401) return;
        const int e = idx % 2401, rest = idx / 2401;
        const int tw = rest & 1, th = (rest >> 1) & 1, head = rest >> 2;
        const int i = e / 49, j = e - i * 49;
        const int yi = i / 7, xi = i - yi * 7, yj = j / 7, xj = j - yj * 7;
        const float v = relb[((yi - yj + 6) * 13 + (xi - xj + 6)) * 6 + head];
        const int hi = th ? 49 + yi : yi, hj = th ? 49 + yj : yj;
        const int wa = tw ? 49 + xi : xi, wb = tw ? 49 + xj : xj;
        const int Li = (hi < 49 ? 0 : (hi < 53 ? 1 : 2)) * 3 + (wa < 49 ? 0 : (wa < 53 ? 1 : 2));
        const int Lj = (hj < 49 ? 0 : (hj < 53 ? 1 : 2)) * 3 + (wb < 49 ? 0 : (wb < 53 ? 1 : 2));
        bm[idx] = (Li != Lj) ? v - 100.0f : v;
    } else {                            // LN1 stats
        const int wave = tid >> 6;
        const int lane = tid & 63;
        const long tok = (long)(bid - 1954) * 4 + wave;
        const float* p = x + tok * 192;
        const float a = p[lane], b = p[lane + 64], c = p[lane + 128];
        float s = a + b + c;
        float q = a * a + b * b + c * c;
        #pragma unroll
        for (int off = 32; off > 0; off >>= 1) {
            s += __shfl_xor(s, off);
            q += __shfl_xor(q, off);
        }
        if (lane == 0) {
            const float m = s * (1.0f / 192.0f);
            const float v = q * (1.0f / 192.0f) - m * m;
            mean[tok] = m;
            rstd[tok] = 1.0f / sqrtf(v + 1e-5f);
        }
    }
}

// ------- fully fused: LN1+shift+window+QKV+attn+proj+LN2+MLP+residuals -----
// Phase A: winattn (round-14 proven, unchanged) -> oa[12] all-head C-layout.
// Phase B: oa -> proj A-frags via Pf roundtrip (Q-phase pattern x6).
// Phase C: proj MFMA from regs + pb + x residual (scattered tok_r rows).
// Phase D: LN2 stats in-register (projmlp proven).
// barrier; Phase E: Xw roundtrip (LDS region 0..24K) -> afrX.
// Phase F: accO = x1 + b2; MLP t-loop (round-14 staging, round-17 S2 pack).
// LDS union 52KB -> 3 blocks/CU.
__global__ __launch_bounds__(256, 3)
void winfull_k(const float* __restrict__ x, const float* __restrict__ n1g,
               const float* __restrict__ n1b, const short* __restrict__ qkvP,
               const float* __restrict__ qkv_b, const float* __restrict__ bm,
               const float* __restrict__ mean, const float* __restrict__ rstd,
               const short* __restrict__ projP, const float* __restrict__ pb,
               const float* __restrict__ n2g, const float* __restrict__ n2b,
               const short* __restrict__ fc1P, const float* __restrict__ b1,
               const short* __restrict__ fc2P, const float* __restrict__ b2,
               float* __restrict__ outp)
{
    __shared__ __align__(16) char LU[53248];
    short (*Kb)[2048] = (short (*)[2048])(LU);           // [0, 8K)
    short (*Vb)[2048] = (short (*)[2048])(LU + 8192);    // [8K, 16K)
    short (*Pf)[1024] = (short (*)[1024])(LU + 16384);   // [16K, 24K)
    short* S1  = (short*)LU;                             // t-loop: [0, 24K)
    short* S2  = (short*)(LU + 24576);                   // [24K, 48K)
    short* HsB = (short*)(LU + 49152);                   // [48K, 52K)

    const int bw  = blockIdx.x;
    const int tid = threadIdx.x;
    const int b = bw >> 6, wi = bw & 63, wh = wi >> 3, ww = wi & 7;
    const int wave = tid >> 6, lane = tid & 63;
    const int col = lane & 15, rbase = (lane >> 4) << 2;
    const float scale = 0.17677669529663687f;

    // ================= Phase A: windowed attention (round 14) ==============
    const int am = lane & 15;
    const int arow = (wave << 4) + am;
    const int kof = (lane >> 4) << 3;
    short8 afr[6];
    long tokA = 0; float mA = 0.f, rsA = 1.f;
    const bool avalid = arow < 49;
    if (avalid) {
        const int yi = arow / 7, xi = arow - yi * 7;
        int h = wh * 7 + yi + 3; if (h >= 56) h -= 56;
        int w = ww * 7 + xi + 3; if (w >= 56) w -= 56;
        tokA = (long)b * 3136 + h * 56 + w;
        mA = mean[tokA]; rsA = rstd[tokA];
    }
    #pragma unroll
    for (int ks = 0; ks < 6; ++ks) {
        short8 a = {};
        if (avalid) {
            const int k0 = (ks << 5) + kof;
            const float4 v0 = *(const float4*)(x + tokA * 192 + k0);
            const float4 v1 = *(const float4*)(x + tokA * 192 + k0 + 4);
            const float4 g0 = *(const float4*)(n1g + k0);
            const float4 g1 = *(const float4*)(n1g + k0 + 4);
            const float4 e0 = *(const float4*)(n1b + k0);
            const float4 e1 = *(const float4*)(n1b + k0 + 4);
            a[0] = bf16((v0.x - mA) * rsA * g0.x + e0.x);
            a[1] = bf16((v0.y - mA) * rsA * g0.y + e0.y);
            a[2] = bf16((v0.z - mA) * rsA * g0.z + e0.z);
            a[3] = bf16((v0.w - mA) * rsA * g0.w + e0.w);
            a[4] = bf16((v1.x - mA) * rsA * g1.x + e1.x);
            a[5] = bf16((v1.y - mA) * rsA * g1.y + e1.y);
            a[6] = bf16((v1.z - mA) * rsA * g1.z + e1.z);
            a[7] = bf16((v1.w - mA) * rsA * g1.w + e1.w);
        }
        afr[ks] = a;
    }

    short8 qfrag[6];
    #pragma unroll
    for (int nt = 0; nt < 12; ++nt) {
        f32x4 acc = {};
        #pragma unroll
        for (int ks = 0; ks < 6; ++ks) {
            const short8 bfr = *(const short8*)(qkvP + ((nt * 6 + ks) * 64 + lane) * 8);
            acc = __builtin_amdgcn_mfma_f32_16x16x32_bf16(afr[ks], bfr, acc, 0, 0, 0);
        }
        const int hh = nt >> 1, d = ((nt & 1) << 4) + col;
        const float bias = qkv_b[hh * 32 + d];
        #pragma unroll
        for (int r = 0; r < 4; ++r) {
            const int m = rbase + r;
            Pf[wave][((m + (((d >> 3) & 3) << 4)) << 3) + (d & 7)] =
                bf16((acc[r] + bias) * scale);
        }
        if (nt & 1) qfrag[hh] = *(const short8*)&Pf[wave][lane << 3];
    }

    long tok_r[4]; bool iv[4]; int i49[4];
    #pragma unroll
    for (int r = 0; r < 4; ++r) {
        const int i = (wave << 4) + rbase + r;
        iv[r] = i < 49;
        i49[r] = iv[r] ? i * 49 : 0;
        if (iv[r]) {
            const int yi = i / 7, xi = i - yi * 7;
            int h = wh * 7 + yi + 3; if (h >= 56) h -= 56;
            int w = ww * 7 + xi + 3; if (w >= 56) w -= 56;
            tok_r[r] = (long)b * 3136 + h * 56 + w;
        } else tok_r[r] = 0;
    }

    f32x4 oa[12] = {};   // all-head output accumulators [h*2+dt]

    #pragma unroll
    for (int h = 0; h < 6; ++h) {
        const int bs = h & 1;
        #pragma unroll
        for (int half = 0; half < 2; ++half) {
            const int d = (half << 4) + col;
            f32x4 acck = {};
            #pragma unroll
            for (int ks = 0; ks < 6; ++ks) {
                const short8 bfr = *(const short8*)(qkvP +
                    (((12 + 2 * h + half) * 6 + ks) * 64 + lane) * 8);
                acck = __builtin_amdgcn_mfma_f32_16x16x32_bf16(afr[ks], bfr, acck, 0, 0, 0);
            }
            const float biask = qkv_b[192 + h * 32 + d];
            #pragma unroll
            for (int r = 0; r < 4; ++r) {
                const int m = rbase + r;
                Kb[bs][(((wave << 6) + m + (((d >> 3) & 3) << 4)) << 3) + (d & 7)] =
                    bf16(acck[r] + biask);
            }
            f32x4 accv = {};
            #pragma unroll
            for (int ks = 0; ks < 6; ++ks) {
                const short8 bfr = *(const short8*)(qkvP +
                    (((24 + 2 * h + half) * 6 + ks) * 64 + lane) * 8);
                accv = __builtin_amdgcn_mfma_f32_16x16x32_bf16(afr[ks], bfr, accv, 0, 0, 0);
            }
            const float biasv = qkv_b[384 + h * 32 + d];
            #pragma unroll
            for (int r = 0; r < 4; ++r) {
                const int m = rbase + r;
                const int flat = ((((half << 1) + (wave >> 1)) << 6) + col +
                                  ((((wave << 1) + (m >> 3)) & 3) << 4)) * 8 + (m & 7);
                Vb[bs][flat] = bf16(accv[r] + biasv);
            }
        }
        __syncthreads();

        const float* bmp = bm + (((h << 1) + (wh == 7)) * 2 + (ww == 7)) * 2401;
        f32x4 sa[4];
        #pragma unroll
        for (int jt = 0; jt < 4; ++jt) {
            f32x4 z = {};
            const short8 kfr = *(const short8*)&Kb[bs][((jt << 6) + lane) << 3];
            sa[jt] = __builtin_amdgcn_mfma_f32_16x16x32_bf16(qfrag[h], kfr, z, 0, 0, 0);
        }
        float p[4][4];
        #pragma unroll
        for (int jt = 0; jt < 4; ++jt) {
            const int j = (jt << 4) + col;
            #pragma unroll
            for (int r = 0; r < 4; ++r)
                p[jt][r] = (j < 49) ? sa[jt][r] + bmp[i49[r] + j] : -1e30f;
        }
        #pragma unroll
        for (int r = 0; r < 4; ++r) {
            float mx = fmaxf(fmaxf(p[0][r], p[1][r]), fmaxf(p[2][r], p[3][r]));
            mx = fmaxf(mx, __shfl_xor(mx, 1));
            mx = fmaxf(mx, __shfl_xor(mx, 2));
            mx = fmaxf(mx, __shfl_xor(mx, 4));
            mx = fmaxf(mx, __shfl_xor(mx, 8));
            float sum = 0.f;
            #pragma unroll
            for (int jt = 0; jt < 4; ++jt) {
                const float e = (((jt << 4) + col) < 49) ? __expf(p[jt][r] - mx) : 0.f;
                p[jt][r] = e; sum += e;
            }
            sum += __shfl_xor(sum, 1);
            sum += __shfl_xor(sum, 2);
            sum += __shfl_xor(sum, 4);
            sum += __shfl_xor(sum, 8);
            const float inv = 1.0f / sum;
            #pragma unroll
            for (int jt = 0; jt < 4; ++jt) p[jt][r] *= inv;
        }
        #pragma unroll
        for (int jt = 0; jt < 4; ++jt) {
            #pragma unroll
            for (int r = 0; r < 4; ++r) {
                const int m = rbase + r;
                const int flat = (((jt >> 1) << 6) + m +
                                  ((((jt & 1) << 1) + (col >> 3)) << 4)) * 8 + (col & 7);
                Pf[wave][flat] = bf16(p[jt][r]);
            }
        }
        const short8 p0 = *(const short8*)&Pf[wave][lane << 3];
        const short8 p1 = *(const short8*)&Pf[wave][(64 + lane) << 3];
        #pragma unroll
        for (int dt = 0; dt < 2; ++dt) {
            const short8 v0 = *(const short8*)&Vb[bs][(((dt << 1) << 6) + lane) << 3];
            const short8 v1 = *(const short8*)&Vb[bs][((((dt << 1) + 1) << 6) + lane) << 3];
            oa[h * 2 + dt] = __builtin_amdgcn_mfma_f32_16x16x32_bf16(p0, v0, oa[h * 2 + dt], 0, 0, 0);
            oa[h * 2 + dt] = __builtin_amdgcn_mfma_f32_16x16x32_bf16(p1, v1, oa[h * 2 + dt], 0, 0, 0);
        }
    }

    // ====== Phase B: oa (C-layout) -> proj A-frags via Pf roundtrip ========
    short8 afrA[6];
    #pragma unroll
    for (int g = 0; g < 6; ++g) {
        #pragma unroll
        for (int dt = 0; dt < 2; ++dt) {
            const int d = (dt << 4) + col;
            #pragma unroll
            for (int r = 0; r < 4; ++r) {
                const int m = rbase + r;
                Pf[wave][((m + (((d >> 3) & 3) << 4)) << 3) + (d & 7)] =
                    bf16(oa[g * 2 + dt][r]);
            }
        }
        afrA[g] = *(const short8*)&Pf[wave][lane << 3];
    }

    // ====== Phase C: proj GEMM from regs + pb + x residual =================
    f32x4 x1a[12] = {};
    #pragma unroll
    for (int ks = 0; ks < 6; ++ks) {
        #pragma unroll
        for (int nt = 0; nt < 12; ++nt) {
            const short8 bfr = *(const short8*)(projP + ks * 6144 + (nt << 9) + (lane << 3));
            x1a[nt] = __builtin_amdgcn_mfma_f32_16x16x32_bf16(afrA[ks], bfr, x1a[nt], 0, 0, 0);
        }
    }
    #pragma unroll
    for (int nt = 0; nt < 12; ++nt) {
        const int n = (nt << 4) + col;
        const float bias = pb[n];
        #pragma unroll
        for (int r = 0; r < 4; ++r)
            x1a[nt][r] += bias + x[tok_r[r] * 192 + n];
    }

    // ====== Phase D: LN2 stats in-register (projmlp proven) ================
    float s0 = 0.f, s1_ = 0.f, s2_ = 0.f, s3 = 0.f;
    float q0 = 0.f, q1 = 0.f, q2 = 0.f, q3 = 0.f;
    #pragma unroll
    for (int nt = 0; nt < 12; ++nt) {
        s0 += x1a[nt][0]; q0 += x1a[nt][0] * x1a[nt][0];
        s1_ += x1a[nt][1]; q1 += x1a[nt][1] * x1a[nt][1];
        s2_ += x1a[nt][2]; q2 += x1a[nt][2] * x1a[nt][2];
        s3 += x1a[nt][3]; q3 += x1a[nt][3] * x1a[nt][3];
    }
    #pragma unroll
    for (int off = 8; off > 0; off >>= 1) {
        s0 += __shfl_xor(s0, off); q0 += __shfl_xor(q0, off);
        s1_ += __shfl_xor(s1_, off); q1 += __shfl_xor(q1, off);
        s2_ += __shfl_xor(s2_, off); q2 += __shfl_xor(q2, off);
        s3 += __shfl_xor(s3, off); q3 += __shfl_xor(q3, off);
    }
    float mr[4], rr[4];
    mr[0] = s0 * (1.0f / 192.0f); rr[0] = rsqrtf(q0 * (1.0f / 192.0f) - mr[0] * mr[0] + 1e-5f);
    mr[1] = s1_ * (1.0f / 192.0f); rr[1] = rsqrtf(q1 * (1.0f / 192.0f) - mr[1] * mr[1] + 1e-5f);
    mr[2] = s2_ * (1.0f / 192.0f); rr[2] = rsqrtf(q2 * (1.0f / 192.0f) - mr[2] * mr[2] + 1e-5f);
    mr[3] = s3 * (1.0f / 192.0f); rr[3] = rsqrtf(q3 * (1.0f / 192.0f) - mr[3] * mr[3] + 1e-5f);

    __syncthreads();   // all waves done with Kb/Vb/Pf before Xw reuses [0,24K)

    // ====== Phase E: LN2(x1) A-frags via Xw roundtrip (region 0..24K) ======
    short* Xw = (short*)LU + wave * 3072;
    #pragma unroll
    for (int nt = 0; nt < 12; ++nt) {
        const int k = (nt << 4) + col;
        const float g = n2g[k], bb = n2b[k];
        #pragma unroll
        for (int r = 0; r < 4; ++r) {
            const int row16 = rbase + r;
            const int flat = (((k >> 5) << 6) + (((k >> 3) & 3) << 4) + row16) * 8 + (k & 7);
            Xw[flat] = bf16((x1a[nt][r] - mr[r]) * rr[r] * g + bb);
        }
    }
    short8 afrX[6];
    #pragma unroll
    for (int ks = 0; ks < 6; ++ks)
        afrX[ks] = *(const short8*)(Xw + (((ks << 6) + lane) << 3));

    // ====== Phase F: accO = x1 + b2; MLP t-loop ============================
    f32x4 accO[12];
    #pragma unroll
    for (int nt = 0; nt < 12; ++nt) {
        const float bias = b2[(nt << 4) + col];
        #pragma unroll
        for (int r = 0; r < 4; ++r)
            accO[nt][r] = x1a[nt][r] + bias;
    }
    // x1a dead from here on.

    short* Hw = HsB + wave * 512;
    for (int t = 0; t < 12; ++t) {
        __syncthreads();               // all waves done reading S (or Xw)
        {
            const short* f1 = fc1P + t * 12288;
            const short* f2 = fc2P + t * 12288;
            #pragma unroll
            for (int i = 0; i < 6; ++i) {
                const int slot = (i << 8) + (wave << 6);   // short8 units
                gll16(f1 + ((slot + lane) << 3), S1 + (slot << 3));
                gll16(f2 + ((slot + lane) << 3), S2 + (slot << 3));
            }
        }
        __syncthreads();               // drains vmcnt -> tiles visible
        // GEMM1: H(16x64 per wave) = afrX @ fc1_tile
        f32x4 accH[4] = {};
        #pragma unroll
        for (int ks = 0; ks < 6; ++ks) {
            #pragma unroll
            for (int nt = 0; nt < 4; ++nt) {
                const short8 bfr = *(const short8*)&S1[((nt * 6 + ks) << 9) + (lane << 3)];
                accH[nt] = __builtin_amdgcn_mfma_f32_16x16x32_bf16(afrX[ks], bfr, accH[nt], 0, 0, 0);
            }
        }
        // bias + exact GELU -> Hw half-slices; GEMM2 per half (wave-private)
        #pragma unroll
        for (int hf = 0; hf < 2; ++hf) {
            #pragma unroll
            for (int ntl = 0; ntl < 2; ++ntl) {
                const int nt = (hf << 1) + ntl;
                const int kh = (nt << 4) + col;
                const float bias = b1[(t << 6) + kh];
                #pragma unroll
                for (int r = 0; r < 4; ++r) {
                    const int m = rbase + r;
                    float val = accH[nt][r] + bias;
                    val = 0.5f * val * (1.0f + erff(val * 0.7071067811865476f));
                    const int flat = ((((kh >> 3) & 3) << 4) + m) * 8 + (kh & 7);
                    Hw[flat] = bf16(val);
                }
            }
            const short8 a = *(const short8*)(Hw + (lane << 3));
            #pragma unroll
            for (int nt2 = 0; nt2 < 12; ++nt2) {   // S2 is [ks][nt] packed
                const short8 bfr = *(const short8*)&S2[((hf * 12 + nt2) << 9) + (lane << 3)];
                accO[nt2] = __builtin_amdgcn_mfma_f32_16x16x32_bf16(a, bfr, accO[nt2], 0, 0, 0);
            }
        }
    }

    // ---- epilogue: out = accO, scattered token rows (valid rows only) ----
    #pragma unroll
    for (int nt = 0; nt < 12; ++nt) {
        const int n = (nt << 4) + col;
        #pragma unroll
        for (int r = 0; r < 4; ++r)
            if (iv[r])
                outp[tok_r[r] * 192 + n] = accO[nt][r];
    }
}

// ---------------------------------------------------------------------------
extern "C" void kernel_launch(void* const* d_in, const int* in_sizes, int n_in,
                              void* d_out, int out_size, void* d_ws, size_t ws_size,
                              hipStream_t stream)
{
    const float* x      = (const float*)d_in[0];
    const float* n1g    = (const float*)d_in[1];
    const float* n1b    = (const float*)d_in[2];
    const float* qkv_w  = (const float*)d_in[3];
    const float* qkv_b  = (const float*)d_in[4];
    const float* relb   = (const float*)d_in[5];
    const float* proj_w = (const float*)d_in[6];
    const float* proj_b = (const float*)d_in[7];
    const float* n2g    = (const float*)d_in[8];
    const float* n2b    = (const float*)d_in[9];
    const float* fc1_w  = (const float*)d_in[10];
    const float* fc1_b  = (const float*)d_in[11];
    const float* fc2_w  = (const float*)d_in[12];
    const float* fc2_b  = (const float*)d_in[13];
    float* out = (float*)d_out;
    char*  ws  = (char*)d_ws;

    float* mb    = (float*)(ws);                   //   401,408 B
    float* rb    = (float*)(ws +   401408L);       //   401,408 B
    short* qkvP  = (short*)(ws +   802816L);       //   221,184 B
    short* projP = (short*)(ws +  1024000L);       //    73,728 B
    short* fc1P  = (short*)(ws +  1097728L);       //   294,912 B
    short* fc2P  = (short*)(ws +  1392640L);       //   294,912 B
    float* bmT   = (float*)(ws +  1687552L);       //   230,496 B  (~1.92 MB total)

    // 1) all prep (packs, bias table, LN1 stats) in one launch
    prep_k<<<1954 + T / 4, 256, 0, stream>>>(qkv_w, proj_w, fc1_w, fc2_w,
                                             relb, x, qkvP, projP, fc1P,
                                             fc2P, bmT, mb, rb);
    // 2) fully fused block: LN1+shift+window+QKV+attn+proj+LN2+MLP+residuals
    winfull_k<<<2048, 256, 0, stream>>>(x, n1g, n1b, qkvP, qkv_b, bmT,
                                        mb, rb, projP, proj_b, n2g, n2b,
                                        fc1P, fc1_b, fc2P, fc2_b, out);
}